// Round 11
// baseline (534.434 us; speedup 1.0000x reference)
//
#include <hip/hip_runtime.h>
#include <hip/hip_bf16.h>

#define NN 50000
#define NE 600000
#define D 128
#define NREL 2
#define BM 128
#define NBIN 512

typedef __attribute__((ext_vector_type(8))) short bf16x8;   // 8 bf16 (4 VGPRs)
typedef __attribute__((ext_vector_type(4))) float f32x4;    // 4 fp32 acc
typedef __attribute__((ext_vector_type(2))) float f32x2;    // packed pair

__device__ __forceinline__ float bf2f(short s) {
    return __uint_as_float(((unsigned int)(unsigned short)s) << 16);
}
__device__ __forceinline__ bf16x8 pack_bf8(const float* a) {
    union { bf16x8 v; __hip_bfloat162 h2[4]; } o;
#pragma unroll
    for (int i = 0; i < 4; i++)
        o.h2[i] = __float22bfloat162_rn(make_float2(a[2 * i], a[2 * i + 1]));
    return o.v;
}

#define NEB ((NE + 255) / 256)          // edge blocks
#define NWT (16384 + 3 * 49152)         // wt elements
#define NWB ((NWT + 255) / 256)         // prep_w blocks

// ---------------- fused: edge count (blocks < NEB) + weight prep (rest) ------
__global__ void k_pre1(const float* __restrict__ attr,
                       const int* __restrict__ dst,
                       int* __restrict__ cnt,
                       const float* __restrict__ Wf,
                       const float* __restrict__ cw,
                       const float* __restrict__ cr,
                       __hip_bfloat16* __restrict__ wt) {
    if (blockIdx.x < NEB) {
        int i = blockIdx.x * blockDim.x + threadIdx.x;
        if (i >= NE) return;
        float2 a = reinterpret_cast<const float2*>(attr)[i];
        int r = (a.y > a.x) ? 1 : 0;   // argmax, first-index tiebreak
        atomicAdd(&cnt[dst[i] * 2 + r], 1);
    } else {
        int idx = (blockIdx.x - NEB) * blockDim.x + threadIdx.x;
        if (idx >= NWT) return;
        float v;
        if (idx < 16384) {
            int n = idx >> 7, k = idx & 127;
            v = Wf[k * 128 + n];
        } else {
            int j = idx - 16384;
            int l = j / 49152; j %= 49152;
            int n = j / 384, k = j % 384;
            if (k < 128)      v = cr[((size_t)l * 128 + k) * 128 + n];
            else if (k < 256) v = cw[((size_t)(l * 2 + 0) * 128 + (k - 128)) * 128 + n];
            else              v = cw[((size_t)(l * 2 + 1) * 128 + (k - 256)) * 128 + n];
        }
        wt[idx] = __float2bfloat16(v);
    }
}

// ---------------- inv + per-NODE bucket allocator + degree histogram ---------
__global__ void k_pre2(const int* __restrict__ cnt, float* __restrict__ inv,
                       int* __restrict__ off, int* __restrict__ cur,
                       int* __restrict__ total, int* __restrict__ hist) {
    int i = blockIdx.x * blockDim.x + threadIdx.x;
    if (i >= NN) return;
    int c0 = cnt[2 * i], c1 = cnt[2 * i + 1];
    inv[2 * i]     = 1.0f / (float)(c0 > 1 ? c0 : 1);
    inv[2 * i + 1] = 1.0f / (float)(c1 > 1 ? c1 : 1);
    int o = atomicAdd(total, c0 + c1);   // wave-coalesced by atomic optimizer
    off[2 * i] = o;       cur[2 * i] = o;
    off[2 * i + 1] = o + c0; cur[2 * i + 1] = o + c0;
    int b = c0 + c1; if (b > NBIN - 1) b = NBIN - 1;
    atomicAdd(&hist[b], 1);              // degree histogram for counting sort
}

// ---------------- descending-degree bin offsets (one 512-thread block) -------
// cursor[b] = #nodes with degree-bin > b  (start of bin b in descending order)
__global__ __launch_bounds__(NBIN)
void k_pre3(const int* __restrict__ hist, int* __restrict__ cursor) {
    __shared__ int s[NBIN];
    int t = threadIdx.x;
    s[t] = hist[NBIN - 1 - t];
    __syncthreads();
    for (int d = 1; d < NBIN; d <<= 1) {
        int v = (t >= d) ? s[t - d] : 0;
        __syncthreads();
        s[t] += v;
        __syncthreads();
    }
    // s[511-b] = sum_{b'>=b} hist[b'] ; exclusive-greater = that - hist[b]
    cursor[t] = s[NBIN - 1 - t] - hist[t];
}

// ---------------- scatter nodes into degree-sorted order ---------------------
__global__ void k_pre4(const int* __restrict__ cnt, int* __restrict__ cursor,
                       int* __restrict__ order) {
    int i = blockIdx.x * blockDim.x + threadIdx.x;
    if (i >= NN) return;
    int b = cnt[2 * i] + cnt[2 * i + 1];
    if (b > NBIN - 1) b = NBIN - 1;
    int pos = atomicAdd(&cursor[b], 1);
    order[pos] = i;
}

// ---------------- fill CSR: srcs[pos] = src[e], bucketed by (dst,rel) --------
__global__ void k_fill(const float* __restrict__ attr,
                       const int* __restrict__ src, const int* __restrict__ dst,
                       int* __restrict__ cursor, int* __restrict__ srcs, int E) {
    int i = blockIdx.x * blockDim.x + threadIdx.x;
    if (i >= E) return;
    float2 a = reinterpret_cast<const float2*>(attr)[i];
    int r = (a.y > a.x) ? 1 : 0;
    int pos = atomicAdd(&cursor[dst[i] * 2 + r], 1);
    srcs[pos] = src[i];
}

// ---------------- aggregation: one 16-lane group per NODE, 4 nodes/wave ------
// Nodes are processed in descending-degree order (order[]), so the 4 groups of
// a wave have near-equal c01 -> cmax ~ c01, ~zero padding iterations.
// Loop bound cmax is wave-uniform so every __shfl runs full-exec (R5 lesson).
// Relation mask + 1/deg fold into per-edge scalar weight -> v_pk_fma_f32.
__global__ __launch_bounds__(256)
void k_aggregate(const __hip_bfloat16* __restrict__ h,
                 const int* __restrict__ srcs,
                 const int* __restrict__ off, const int* __restrict__ cnt,
                 const float* __restrict__ inv,
                 const int* __restrict__ order,
                 __hip_bfloat16* __restrict__ agg) {
    int wid = (blockIdx.x * blockDim.x + threadIdx.x) >> 6;   // wave id
    int lane = threadIdx.x & 63;
    int nb = wid * 4;
    if (nb >= NN) return;                  // whole-wave uniform (NN%4==0)
    const int g = lane >> 4, l16 = lane & 15;
    int node = order[nb + g];              // degree-sorted; always valid

    int st  = off[2 * node];
    int c0  = cnt[2 * node];
    int c01 = c0 + cnt[2 * node + 1];
    float i0 = inv[2 * node], i1 = inv[2 * node + 1];

    int sv = (l16 < c01) ? srcs[st + l16] : 0;   // group-coalesced index load

    int cm = c01;                                 // wave max of c01
    cm = max(cm, __shfl_xor(cm, 16));
    cm = max(cm, __shfl_xor(cm, 32));

    f32x2 a0[4], a1[4];
#pragma unroll
    for (int p = 0; p < 4; p++) { a0[p] = (f32x2)(0.f); a1[p] = (f32x2)(0.f); }

    const char* hb = (const char*)h;
    if (cm <= 16) {                               // common case (sorted waves)
        for (int j = 0; j < cm; j += 4) {         // wave-uniform trip count
            int s[4]; float w0[4], w1[4];
#pragma unroll
            for (int q = 0; q < 4; ++q) {
                int jj = j + q;
                int t = __shfl(sv, (lane & 48) + (jj & 15));  // full-exec shfl
                s[q] = (jj < c01) ? t : 0;        // clamp: row 0 valid, L1-hot
                w0[q] = (jj < c0) ? i0 : 0.f;
                w1[q] = (jj >= c0 && jj < c01) ? i1 : 0.f;
            }
            uint4 v[4];
#pragma unroll
            for (int q = 0; q < 4; ++q)           // 4 independent gathers/lane
                v[q] = *reinterpret_cast<const uint4*>(
                    hb + (size_t)s[q] * 256 + l16 * 16);
#pragma unroll
            for (int q = 0; q < 4; ++q) {
                f32x2 w0v = {w0[q], w0[q]}, w1v = {w1[q], w1[q]};
                unsigned uu[4] = {v[q].x, v[q].y, v[q].z, v[q].w};
#pragma unroll
                for (int p = 0; p < 4; ++p) {
                    f32x2 val;
                    val.x = __uint_as_float(uu[p] << 16);
                    val.y = __uint_as_float(uu[p] & 0xffff0000u);
                    a0[p] += val * w0v;           // v_pk_fma_f32
                    a1[p] += val * w1v;
                }
            }
        }
    } else {                                      // hub waves (few, sorted)
        for (int j = 0; j < cm; j += 4) {
            int s[4]; float w0[4], w1[4];
#pragma unroll
            for (int q = 0; q < 4; ++q) {
                int jj = j + q;
                int t = __shfl(sv, (lane & 48) + (jj & 15));
                s[q] = t;
                if (jj >= 16 && jj < c01) s[q] = srcs[st + jj];
                if (jj >= c01) s[q] = 0;
                w0[q] = (jj < c0) ? i0 : 0.f;
                w1[q] = (jj >= c0 && jj < c01) ? i1 : 0.f;
            }
            uint4 v[4];
#pragma unroll
            for (int q = 0; q < 4; ++q)
                v[q] = *reinterpret_cast<const uint4*>(
                    hb + (size_t)s[q] * 256 + l16 * 16);
#pragma unroll
            for (int q = 0; q < 4; ++q) {
                f32x2 w0v = {w0[q], w0[q]}, w1v = {w1[q], w1[q]};
                unsigned uu[4] = {v[q].x, v[q].y, v[q].z, v[q].w};
#pragma unroll
                for (int p = 0; p < 4; ++p) {
                    f32x2 val;
                    val.x = __uint_as_float(uu[p] << 16);
                    val.y = __uint_as_float(uu[p] & 0xffff0000u);
                    a0[p] += val * w0v;
                    a1[p] += val * w1v;
                }
            }
        }
    }

    float t0[8], t1[8];
#pragma unroll
    for (int p = 0; p < 4; p++) {
        t0[2 * p] = a0[p].x; t0[2 * p + 1] = a0[p].y;
        t1[2 * p] = a1[p].x; t1[2 * p + 1] = a1[p].y;
    }
    __hip_bfloat16* dp = agg + (size_t)node * 256;
    *reinterpret_cast<bf16x8*>(dp + l16 * 8)       = pack_bf8(t0);
    *reinterpret_cast<bf16x8*>(dp + 128 + l16 * 8) = pack_bf8(t1);
}

// ---------------- proj GEMM: h0 = relu(x_f32 @ Wtp^T + bf), bf16 out ---------
__global__ __launch_bounds__(256)
void k_gemm_proj(const float* __restrict__ X,
                 const __hip_bfloat16* __restrict__ Wt,   // [128][128]
                 const float* __restrict__ bias,
                 __hip_bfloat16* __restrict__ out, int N) {
    __shared__ uint4 sB4[1024];            // 16 KB
    char* sB = (char*)sB4;
    const int tid = threadIdx.x;
    const int w = tid >> 6;
    const int l16 = tid & 15, lg = (tid & 63) >> 4;

    f32x4 acc[2][8];
#pragma unroll
    for (int m = 0; m < 2; m++)
#pragma unroll
        for (int n = 0; n < 8; n++) acc[m][n] = (f32x4)(0.f);

    const int row0 = blockIdx.x * 128;
#pragma unroll
    for (int kb = 0; kb < 2; ++kb) {
        bf16x8 afr[2][2];
#pragma unroll
        for (int mb = 0; mb < 2; ++mb)
#pragma unroll
            for (int kk = 0; kk < 2; ++kk) {
                int r = row0 + w * 32 + mb * 16 + l16;
                if (r >= N) r = N - 1;
                const float* p = X + (size_t)r * D + kb * 64 + kk * 32 + lg * 8;
                float4 u0 = reinterpret_cast<const float4*>(p)[0];
                float4 u1 = reinterpret_cast<const float4*>(p)[1];
                float t[8] = {u0.x, u0.y, u0.z, u0.w, u1.x, u1.y, u1.z, u1.w};
                afr[mb][kk] = pack_bf8(t);
            }
        __syncthreads();
        {
            int trow = tid >> 3, tb = (tid & 7) * 16;
#pragma unroll
            for (int p = 0; p < 4; ++p) {
                int rr = trow + p * 32;
                uint4 v = *reinterpret_cast<const uint4*>(
                    (const char*)(Wt + (size_t)rr * 128 + kb * 64) + tb);
                *reinterpret_cast<uint4*>(sB + rr * 128 + (tb ^ ((rr & 7) << 4))) = v;
            }
        }
        __syncthreads();
#pragma unroll
        for (int kk = 0; kk < 2; ++kk)
#pragma unroll
            for (int nb = 0; nb < 8; ++nb) {
                int brow = nb * 16 + l16;
                int bcol = kk * 64 + lg * 16;
                bf16x8 bfr = *reinterpret_cast<const bf16x8*>(
                    sB + brow * 128 + (bcol ^ ((brow & 7) << 4)));
                acc[0][nb] = __builtin_amdgcn_mfma_f32_16x16x32_bf16(
                    afr[0][kk], bfr, acc[0][nb], 0, 0, 0);
                acc[1][nb] = __builtin_amdgcn_mfma_f32_16x16x32_bf16(
                    afr[1][kk], bfr, acc[1][nb], 0, 0, 0);
            }
    }
#pragma unroll
    for (int nb = 0; nb < 8; ++nb) {
        int n = nb * 16 + l16;
        float bv = bias[n];
#pragma unroll
        for (int mb = 0; mb < 2; ++mb)
#pragma unroll
            for (int r = 0; r < 4; ++r) {
                int grow = row0 + w * 32 + mb * 16 + lg * 4 + r;
                if (grow < N) {
                    float v = acc[mb][nb][r] + bv;
                    v = v > 0.f ? v : 0.f;
                    out[(size_t)grow * D + n] = __float2bfloat16(v);
                }
            }
    }
}

// ---------------- MFMA GEMM: out = relu([A0|A1|A2] @ Wt^T + bias) ------------
// Per-chunk row stride (elements): hin is 128, agg (interleaved) is 256.
template <bool OUT_F32>
__global__ __launch_bounds__(256)
void k_gemm_mfma(const __hip_bfloat16* __restrict__ A0, int sA0,
                 const __hip_bfloat16* __restrict__ A1, int sA1,
                 const __hip_bfloat16* __restrict__ A2, int sA2,
                 const __hip_bfloat16* __restrict__ Wt,   // [128][384]
                 const float* __restrict__ bias,
                 void* __restrict__ outv, int N) {
    __shared__ uint4 sB4[1024];            // 16 KB
    char* sB = (char*)sB4;
    const int tid = threadIdx.x;
    const int w = tid >> 6;
    const int l16 = tid & 15, lg = (tid & 63) >> 4;
    const __hip_bfloat16* As[3] = {A0, A1, A2};
    const int strides[3] = {sA0, sA1, sA2};

    f32x4 acc[2][8];
#pragma unroll
    for (int m = 0; m < 2; m++)
#pragma unroll
        for (int n = 0; n < 8; n++) acc[m][n] = (f32x4)(0.f);

    const size_t row0 = (size_t)blockIdx.x * BM;
#pragma unroll
    for (int kb = 0; kb < 6; ++kb) {
        const __hip_bfloat16* Ac = As[kb >> 1];
        const int strideC = strides[kb >> 1];
        const int koff = (kb & 1) * 64;
        bf16x8 afr[2][2];
#pragma unroll
        for (int mb = 0; mb < 2; ++mb)
#pragma unroll
            for (int kk = 0; kk < 2; ++kk) {
                int r = (int)row0 + w * 32 + mb * 16 + l16;
                if (r >= N) r = N - 1;              // clamped; store-guarded later
                afr[mb][kk] = *reinterpret_cast<const bf16x8*>(
                    Ac + (size_t)r * strideC + koff + kk * 32 + lg * 8);
            }
        __syncthreads();   // previous kb's sB reads complete
        {
            int trow = tid >> 3;
            int tb = (tid & 7) * 16;               // byte col within 128B row
#pragma unroll
            for (int p = 0; p < 4; ++p) {
                int rr = trow + p * 32;
                uint4 v = *reinterpret_cast<const uint4*>(
                    (const char*)(Wt + (size_t)rr * 384 + kb * 64) + tb);
                *reinterpret_cast<uint4*>(sB + rr * 128 + (tb ^ ((rr & 7) << 4))) = v;
            }
        }
        __syncthreads();
#pragma unroll
        for (int kk = 0; kk < 2; ++kk) {
#pragma unroll
            for (int nb = 0; nb < 8; ++nb) {
                int brow = nb * 16 + l16;
                int bcol = kk * 64 + lg * 16;
                bf16x8 bfr = *reinterpret_cast<const bf16x8*>(
                    sB + brow * 128 + (bcol ^ ((brow & 7) << 4)));
                acc[0][nb] = __builtin_amdgcn_mfma_f32_16x16x32_bf16(
                    afr[0][kk], bfr, acc[0][nb], 0, 0, 0);
                acc[1][nb] = __builtin_amdgcn_mfma_f32_16x16x32_bf16(
                    afr[1][kk], bfr, acc[1][nb], 0, 0, 0);
            }
        }
    }
#pragma unroll
    for (int nb = 0; nb < 8; ++nb) {
        int n = nb * 16 + l16;
        float bv = bias[n];
#pragma unroll
        for (int mb = 0; mb < 2; ++mb) {
#pragma unroll
            for (int r = 0; r < 4; ++r) {
                long grow = (long)row0 + w * 32 + mb * 16 + lg * 4 + r;
                if (grow < N) {
                    float v = acc[mb][nb][r] + bv;
                    v = v > 0.f ? v : 0.f;
                    if (OUT_F32)
                        ((float*)outv)[(size_t)grow * D + n] = v;
                    else
                        ((__hip_bfloat16*)outv)[(size_t)grow * D + n] =
                            __float2bfloat16(v);
                }
            }
        }
    }
}

extern "C" void kernel_launch(void* const* d_in, const int* in_sizes, int n_in,
                              void* d_out, int out_size, void* d_ws, size_t ws_size,
                              hipStream_t stream) {
    const float* x    = (const float*)d_in[0];
    const int*   ei   = (const int*)d_in[1];
    const float* attr = (const float*)d_in[2];
    const float* Wf   = (const float*)d_in[3];
    const float* bf   = (const float*)d_in[4];
    const float* cw   = (const float*)d_in[5];  // [3][2][128][128]
    const float* cr   = (const float*)d_in[6];  // [3][128][128]
    const float* cb   = (const float*)d_in[7];  // [3][128]
    const int* src  = ei;
    const int* dstv = ei + NE;

    // workspace layout (bytes)
    char* p = (char*)d_ws;
    __hip_bfloat16* h0   = (__hip_bfloat16*)p; p += (size_t)NN * D * 2;
    __hip_bfloat16* h1   = (__hip_bfloat16*)p; p += (size_t)NN * D * 2;
    __hip_bfloat16* aggb = (__hip_bfloat16*)p; p += (size_t)2 * NN * D * 2;
    __hip_bfloat16* wt   = (__hip_bfloat16*)p; p += (size_t)NWT * 2;
    float* inv  = (float*)p;                p += (size_t)2 * NN * 4;
    // --- contiguous zero-init region: cnt | hist | total ---
    int*   cnt  = (int*)p;                  p += (size_t)2 * NN * 4;
    int*   hist = (int*)p;                  p += (size_t)NBIN * 4;
    int*   total= (int*)p;                  p += 4;
    // -------------------------------------------------------
    int*   off  = (int*)p;                  p += (size_t)2 * NN * 4;
    int*   cur  = (int*)p;                  p += (size_t)2 * NN * 4;
    int*   bcur = (int*)p;                  p += (size_t)NBIN * 4;
    int*   order= (int*)p;                  p += (size_t)NN * 4;
    int*   srcs = (int*)p;

    float* outp = (float*)d_out;

    // ---- layer-invariant preprocessing ----
    hipMemsetAsync(cnt, 0, (size_t)(2 * NN + NBIN + 1) * sizeof(int), stream);
    k_pre1<<<NEB + NWB, 256, 0, stream>>>(attr, dstv, cnt, Wf, cw, cr, wt);
    k_pre2<<<(NN + 255) / 256, 256, 0, stream>>>(cnt, inv, off, cur, total, hist);
    k_pre3<<<1, NBIN, 0, stream>>>(hist, bcur);
    k_pre4<<<(NN + 255) / 256, 256, 0, stream>>>(cnt, bcur, order);
    k_fill<<<NEB, 256, 0, stream>>>(attr, src, dstv, cur, srcs, NE);

    // input projection (f32 x read directly)
    k_gemm_proj<<<(NN + 127) / 128, 256, 0, stream>>>(x, wt, bf, h0, NN);

    const int gblocks = (NN + BM - 1) / BM;
    const int ablocks = ((NN + 3) / 4 * 64 + 255) / 256;  // 16-lane group/node
    for (int l = 0; l < 3; ++l) {
        const __hip_bfloat16* hin = (l == 1) ? h1 : h0;
        k_aggregate<<<ablocks, 256, 0, stream>>>(hin, srcs, off, cnt, inv,
                                                 order, aggb);
        const __hip_bfloat16* wl = wt + 16384 + (size_t)l * 49152;
        const float* bl = cb + (size_t)l * D;
        if (l == 2) {
            k_gemm_mfma<true><<<gblocks, 256, 0, stream>>>(
                hin, 128, aggb, 256, aggb + 128, 256, wl, bl, outp, NN);
        } else {
            __hip_bfloat16* hout = (l == 0) ? h1 : h0;
            k_gemm_mfma<false><<<gblocks, 256, 0, stream>>>(
                hin, 128, aggb, 256, aggb + 128, 256, wl, bl, hout, NN);
        }
    }
}

// Round 12
// 235.389 us; speedup vs baseline: 2.2704x; 2.2704x over previous
//
#include <hip/hip_runtime.h>
#include <hip/hip_bf16.h>

#define NN 50000
#define NE 600000
#define D 128
#define NREL 2
#define BM 128
#define NBIN 512

typedef __attribute__((ext_vector_type(8))) short bf16x8;   // 8 bf16 (4 VGPRs)
typedef __attribute__((ext_vector_type(4))) float f32x4;    // 4 fp32 acc
typedef __attribute__((ext_vector_type(2))) float f32x2;    // packed pair

__device__ __forceinline__ float bf2f(short s) {
    return __uint_as_float(((unsigned int)(unsigned short)s) << 16);
}
__device__ __forceinline__ bf16x8 pack_bf8(const float* a) {
    union { bf16x8 v; __hip_bfloat162 h2[4]; } o;
#pragma unroll
    for (int i = 0; i < 4; i++)
        o.h2[i] = __float22bfloat162_rn(make_float2(a[2 * i], a[2 * i + 1]));
    return o.v;
}

#define NEB ((NE + 255) / 256)          // edge blocks
#define NWT (16384 + 3 * 49152)         // wt elements
#define NWB ((NWT + 255) / 256)         // prep_w blocks

// ---------------- fused: edge count (blocks < NEB) + weight prep (rest) ------
__global__ void k_pre1(const float* __restrict__ attr,
                       const int* __restrict__ dst,
                       int* __restrict__ cnt,
                       const float* __restrict__ Wf,
                       const float* __restrict__ cw,
                       const float* __restrict__ cr,
                       __hip_bfloat16* __restrict__ wt) {
    if (blockIdx.x < NEB) {
        int i = blockIdx.x * blockDim.x + threadIdx.x;
        if (i >= NE) return;
        float2 a = reinterpret_cast<const float2*>(attr)[i];
        int r = (a.y > a.x) ? 1 : 0;   // argmax, first-index tiebreak
        atomicAdd(&cnt[dst[i] * 2 + r], 1);
    } else {
        int idx = (blockIdx.x - NEB) * blockDim.x + threadIdx.x;
        if (idx >= NWT) return;
        float v;
        if (idx < 16384) {
            int n = idx >> 7, k = idx & 127;
            v = Wf[k * 128 + n];
        } else {
            int j = idx - 16384;
            int l = j / 49152; j %= 49152;
            int n = j / 384, k = j % 384;
            if (k < 128)      v = cr[((size_t)l * 128 + k) * 128 + n];
            else if (k < 256) v = cw[((size_t)(l * 2 + 0) * 128 + (k - 128)) * 128 + n];
            else              v = cw[((size_t)(l * 2 + 1) * 128 + (k - 256)) * 128 + n];
        }
        wt[idx] = __float2bfloat16(v);
    }
}

// ---------------- inv + allocator + degree histogram (LDS pre-aggregated) ----
// R11 lesson: 50k atomics onto ~40 hot bins = ~160us serialized RMW. LDS
// histogram per block + <=nonzero-bin flush cuts global atomics ~64x.
__global__ __launch_bounds__(256)
void k_pre2(const int* __restrict__ cnt, float* __restrict__ inv,
            int* __restrict__ off, int* __restrict__ cur,
            int* __restrict__ total, int* __restrict__ hist) {
    __shared__ int lh[NBIN];
    for (int t = threadIdx.x; t < NBIN; t += 256) lh[t] = 0;
    __syncthreads();
    int i = blockIdx.x * blockDim.x + threadIdx.x;
    if (i < NN) {
        int c0 = cnt[2 * i], c1 = cnt[2 * i + 1];
        inv[2 * i]     = 1.0f / (float)(c0 > 1 ? c0 : 1);
        inv[2 * i + 1] = 1.0f / (float)(c1 > 1 ? c1 : 1);
        int o = atomicAdd(total, c0 + c1);   // single address: wave-coalesced
        off[2 * i] = o;          cur[2 * i] = o;
        off[2 * i + 1] = o + c0; cur[2 * i + 1] = o + c0;
        int b = c0 + c1; if (b > NBIN - 1) b = NBIN - 1;
        atomicAdd(&lh[b], 1);                // LDS atomic: cheap
    }
    __syncthreads();
    for (int t = threadIdx.x; t < NBIN; t += 256) {
        int v = lh[t];
        if (v) atomicAdd(&hist[t], v);       // ~40 global atomics per block
    }
}

// ---------------- descending-degree bin offsets (one 512-thread block) -------
// cursor[b] = #nodes with degree-bin > b  (start of bin b in descending order)
__global__ __launch_bounds__(NBIN)
void k_pre3(const int* __restrict__ hist, int* __restrict__ cursor) {
    __shared__ int s[NBIN];
    int t = threadIdx.x;
    s[t] = hist[NBIN - 1 - t];
    __syncthreads();
    for (int d = 1; d < NBIN; d <<= 1) {
        int v = (t >= d) ? s[t - d] : 0;
        __syncthreads();
        s[t] += v;
        __syncthreads();
    }
    // s[511-b] = sum_{b'>=b} hist[b'] ; exclusive-greater = that - hist[b]
    cursor[t] = s[NBIN - 1 - t] - hist[t];
}

// ---------------- scatter nodes into degree-sorted order (LDS ranges) --------
// Same hot-bin fix: per-block LDS counts + one range-reserve atomic per
// (block,bin); within-bin order is irrelevant (equal degree within a bin).
__global__ __launch_bounds__(256)
void k_pre4(const int* __restrict__ cnt, int* __restrict__ cursor,
            int* __restrict__ order) {
    __shared__ int lh[NBIN];
    __shared__ int lbase[NBIN];
    for (int t = threadIdx.x; t < NBIN; t += 256) lh[t] = 0;
    __syncthreads();
    int i = blockIdx.x * blockDim.x + threadIdx.x;
    int b = 0, lpos = 0;
    bool valid = i < NN;
    if (valid) {
        b = cnt[2 * i] + cnt[2 * i + 1];
        if (b > NBIN - 1) b = NBIN - 1;
        lpos = atomicAdd(&lh[b], 1);         // LDS atomic
    }
    __syncthreads();
    for (int t = threadIdx.x; t < NBIN; t += 256) {
        int v = lh[t];
        lbase[t] = v ? atomicAdd(&cursor[t], v) : 0;   // range reserve
    }
    __syncthreads();
    if (valid) order[lbase[b] + lpos] = i;
}

// ---------------- fill CSR: srcs[pos] = src[e], bucketed by (dst,rel) --------
__global__ void k_fill(const float* __restrict__ attr,
                       const int* __restrict__ src, const int* __restrict__ dst,
                       int* __restrict__ cursor, int* __restrict__ srcs, int E) {
    int i = blockIdx.x * blockDim.x + threadIdx.x;
    if (i >= E) return;
    float2 a = reinterpret_cast<const float2*>(attr)[i];
    int r = (a.y > a.x) ? 1 : 0;
    int pos = atomicAdd(&cursor[dst[i] * 2 + r], 1);
    srcs[pos] = src[i];
}

// ---------------- aggregation: one 16-lane group per NODE, 4 nodes/wave ------
// Nodes processed in descending-degree order (order[]): the 4 groups of a wave
// have near-equal c01 -> cmax ~ c01, ~zero padding. Loop bound cmax is
// wave-uniform so every __shfl runs full-exec (R5 lesson). Relation mask +
// 1/deg fold into per-edge scalar weight -> v_pk_fma_f32 accumulate.
__global__ __launch_bounds__(256)
void k_aggregate(const __hip_bfloat16* __restrict__ h,
                 const int* __restrict__ srcs,
                 const int* __restrict__ off, const int* __restrict__ cnt,
                 const float* __restrict__ inv,
                 const int* __restrict__ order,
                 __hip_bfloat16* __restrict__ agg) {
    int wid = (blockIdx.x * blockDim.x + threadIdx.x) >> 6;   // wave id
    int lane = threadIdx.x & 63;
    int nb = wid * 4;
    if (nb >= NN) return;                  // whole-wave uniform (NN%4==0)
    const int g = lane >> 4, l16 = lane & 15;
    int node = order[nb + g];              // degree-sorted; always valid

    int st  = off[2 * node];
    int c0  = cnt[2 * node];
    int c01 = c0 + cnt[2 * node + 1];
    float i0 = inv[2 * node], i1 = inv[2 * node + 1];

    int sv = (l16 < c01) ? srcs[st + l16] : 0;   // group-coalesced index load

    int cm = c01;                                 // wave max of c01
    cm = max(cm, __shfl_xor(cm, 16));
    cm = max(cm, __shfl_xor(cm, 32));

    f32x2 a0[4], a1[4];
#pragma unroll
    for (int p = 0; p < 4; p++) { a0[p] = (f32x2)(0.f); a1[p] = (f32x2)(0.f); }

    const char* hb = (const char*)h;
    if (cm <= 16) {                               // common case (sorted waves)
        for (int j = 0; j < cm; j += 4) {         // wave-uniform trip count
            int s[4]; float w0[4], w1[4];
#pragma unroll
            for (int q = 0; q < 4; ++q) {
                int jj = j + q;
                int t = __shfl(sv, (lane & 48) + (jj & 15));  // full-exec shfl
                s[q] = (jj < c01) ? t : 0;        // clamp: row 0 valid, L1-hot
                w0[q] = (jj < c0) ? i0 : 0.f;
                w1[q] = (jj >= c0 && jj < c01) ? i1 : 0.f;
            }
            uint4 v[4];
#pragma unroll
            for (int q = 0; q < 4; ++q)           // 4 independent gathers/lane
                v[q] = *reinterpret_cast<const uint4*>(
                    hb + (size_t)s[q] * 256 + l16 * 16);
#pragma unroll
            for (int q = 0; q < 4; ++q) {
                f32x2 w0v = {w0[q], w0[q]}, w1v = {w1[q], w1[q]};
                unsigned uu[4] = {v[q].x, v[q].y, v[q].z, v[q].w};
#pragma unroll
                for (int p = 0; p < 4; ++p) {
                    f32x2 val;
                    val.x = __uint_as_float(uu[p] << 16);
                    val.y = __uint_as_float(uu[p] & 0xffff0000u);
                    a0[p] += val * w0v;           // v_pk_fma_f32
                    a1[p] += val * w1v;
                }
            }
        }
    } else {                                      // hub waves (few, sorted)
        for (int j = 0; j < cm; j += 4) {
            int s[4]; float w0[4], w1[4];
#pragma unroll
            for (int q = 0; q < 4; ++q) {
                int jj = j + q;
                int t = __shfl(sv, (lane & 48) + (jj & 15));
                s[q] = t;
                if (jj >= 16 && jj < c01) s[q] = srcs[st + jj];
                if (jj >= c01) s[q] = 0;
                w0[q] = (jj < c0) ? i0 : 0.f;
                w1[q] = (jj >= c0 && jj < c01) ? i1 : 0.f;
            }
            uint4 v[4];
#pragma unroll
            for (int q = 0; q < 4; ++q)
                v[q] = *reinterpret_cast<const uint4*>(
                    hb + (size_t)s[q] * 256 + l16 * 16);
#pragma unroll
            for (int q = 0; q < 4; ++q) {
                f32x2 w0v = {w0[q], w0[q]}, w1v = {w1[q], w1[q]};
                unsigned uu[4] = {v[q].x, v[q].y, v[q].z, v[q].w};
#pragma unroll
                for (int p = 0; p < 4; ++p) {
                    f32x2 val;
                    val.x = __uint_as_float(uu[p] << 16);
                    val.y = __uint_as_float(uu[p] & 0xffff0000u);
                    a0[p] += val * w0v;
                    a1[p] += val * w1v;
                }
            }
        }
    }

    float t0[8], t1[8];
#pragma unroll
    for (int p = 0; p < 4; p++) {
        t0[2 * p] = a0[p].x; t0[2 * p + 1] = a0[p].y;
        t1[2 * p] = a1[p].x; t1[2 * p + 1] = a1[p].y;
    }
    __hip_bfloat16* dp = agg + (size_t)node * 256;
    *reinterpret_cast<bf16x8*>(dp + l16 * 8)       = pack_bf8(t0);
    *reinterpret_cast<bf16x8*>(dp + 128 + l16 * 8) = pack_bf8(t1);
}

// ---------------- proj GEMM: h0 = relu(x_f32 @ Wtp^T + bf), bf16 out ---------
__global__ __launch_bounds__(256)
void k_gemm_proj(const float* __restrict__ X,
                 const __hip_bfloat16* __restrict__ Wt,   // [128][128]
                 const float* __restrict__ bias,
                 __hip_bfloat16* __restrict__ out, int N) {
    __shared__ uint4 sB4[1024];            // 16 KB
    char* sB = (char*)sB4;
    const int tid = threadIdx.x;
    const int w = tid >> 6;
    const int l16 = tid & 15, lg = (tid & 63) >> 4;

    f32x4 acc[2][8];
#pragma unroll
    for (int m = 0; m < 2; m++)
#pragma unroll
        for (int n = 0; n < 8; n++) acc[m][n] = (f32x4)(0.f);

    const int row0 = blockIdx.x * 128;
#pragma unroll
    for (int kb = 0; kb < 2; ++kb) {
        bf16x8 afr[2][2];
#pragma unroll
        for (int mb = 0; mb < 2; ++mb)
#pragma unroll
            for (int kk = 0; kk < 2; ++kk) {
                int r = row0 + w * 32 + mb * 16 + l16;
                if (r >= N) r = N - 1;
                const float* p = X + (size_t)r * D + kb * 64 + kk * 32 + lg * 8;
                float4 u0 = reinterpret_cast<const float4*>(p)[0];
                float4 u1 = reinterpret_cast<const float4*>(p)[1];
                float t[8] = {u0.x, u0.y, u0.z, u0.w, u1.x, u1.y, u1.z, u1.w};
                afr[mb][kk] = pack_bf8(t);
            }
        __syncthreads();
        {
            int trow = tid >> 3, tb = (tid & 7) * 16;
#pragma unroll
            for (int p = 0; p < 4; ++p) {
                int rr = trow + p * 32;
                uint4 v = *reinterpret_cast<const uint4*>(
                    (const char*)(Wt + (size_t)rr * 128 + kb * 64) + tb);
                *reinterpret_cast<uint4*>(sB + rr * 128 + (tb ^ ((rr & 7) << 4))) = v;
            }
        }
        __syncthreads();
#pragma unroll
        for (int kk = 0; kk < 2; ++kk)
#pragma unroll
            for (int nb = 0; nb < 8; ++nb) {
                int brow = nb * 16 + l16;
                int bcol = kk * 64 + lg * 16;
                bf16x8 bfr = *reinterpret_cast<const bf16x8*>(
                    sB + brow * 128 + (bcol ^ ((brow & 7) << 4)));
                acc[0][nb] = __builtin_amdgcn_mfma_f32_16x16x32_bf16(
                    afr[0][kk], bfr, acc[0][nb], 0, 0, 0);
                acc[1][nb] = __builtin_amdgcn_mfma_f32_16x16x32_bf16(
                    afr[1][kk], bfr, acc[1][nb], 0, 0, 0);
            }
    }
#pragma unroll
    for (int nb = 0; nb < 8; ++nb) {
        int n = nb * 16 + l16;
        float bv = bias[n];
#pragma unroll
        for (int mb = 0; mb < 2; ++mb)
#pragma unroll
            for (int r = 0; r < 4; ++r) {
                int grow = row0 + w * 32 + mb * 16 + lg * 4 + r;
                if (grow < N) {
                    float v = acc[mb][nb][r] + bv;
                    v = v > 0.f ? v : 0.f;
                    out[(size_t)grow * D + n] = __float2bfloat16(v);
                }
            }
    }
}

// ---------------- MFMA GEMM: out = relu([A0|A1|A2] @ Wt^T + bias) ------------
// Per-chunk row stride (elements): hin is 128, agg (interleaved) is 256.
template <bool OUT_F32>
__global__ __launch_bounds__(256)
void k_gemm_mfma(const __hip_bfloat16* __restrict__ A0, int sA0,
                 const __hip_bfloat16* __restrict__ A1, int sA1,
                 const __hip_bfloat16* __restrict__ A2, int sA2,
                 const __hip_bfloat16* __restrict__ Wt,   // [128][384]
                 const float* __restrict__ bias,
                 void* __restrict__ outv, int N) {
    __shared__ uint4 sB4[1024];            // 16 KB
    char* sB = (char*)sB4;
    const int tid = threadIdx.x;
    const int w = tid >> 6;
    const int l16 = tid & 15, lg = (tid & 63) >> 4;
    const __hip_bfloat16* As[3] = {A0, A1, A2};
    const int strides[3] = {sA0, sA1, sA2};

    f32x4 acc[2][8];
#pragma unroll
    for (int m = 0; m < 2; m++)
#pragma unroll
        for (int n = 0; n < 8; n++) acc[m][n] = (f32x4)(0.f);

    const size_t row0 = (size_t)blockIdx.x * BM;
#pragma unroll
    for (int kb = 0; kb < 6; ++kb) {
        const __hip_bfloat16* Ac = As[kb >> 1];
        const int strideC = strides[kb >> 1];
        const int koff = (kb & 1) * 64;
        bf16x8 afr[2][2];
#pragma unroll
        for (int mb = 0; mb < 2; ++mb)
#pragma unroll
            for (int kk = 0; kk < 2; ++kk) {
                int r = (int)row0 + w * 32 + mb * 16 + l16;
                if (r >= N) r = N - 1;              // clamped; store-guarded later
                afr[mb][kk] = *reinterpret_cast<const bf16x8*>(
                    Ac + (size_t)r * strideC + koff + kk * 32 + lg * 8);
            }
        __syncthreads();   // previous kb's sB reads complete
        {
            int trow = tid >> 3;
            int tb = (tid & 7) * 16;               // byte col within 128B row
#pragma unroll
            for (int p = 0; p < 4; ++p) {
                int rr = trow + p * 32;
                uint4 v = *reinterpret_cast<const uint4*>(
                    (const char*)(Wt + (size_t)rr * 384 + kb * 64) + tb);
                *reinterpret_cast<uint4*>(sB + rr * 128 + (tb ^ ((rr & 7) << 4))) = v;
            }
        }
        __syncthreads();
#pragma unroll
        for (int kk = 0; kk < 2; ++kk) {
#pragma unroll
            for (int nb = 0; nb < 8; ++nb) {
                int brow = nb * 16 + l16;
                int bcol = kk * 64 + lg * 16;
                bf16x8 bfr = *reinterpret_cast<const bf16x8*>(
                    sB + brow * 128 + (bcol ^ ((brow & 7) << 4)));
                acc[0][nb] = __builtin_amdgcn_mfma_f32_16x16x32_bf16(
                    afr[0][kk], bfr, acc[0][nb], 0, 0, 0);
                acc[1][nb] = __builtin_amdgcn_mfma_f32_16x16x32_bf16(
                    afr[1][kk], bfr, acc[1][nb], 0, 0, 0);
            }
        }
    }
#pragma unroll
    for (int nb = 0; nb < 8; ++nb) {
        int n = nb * 16 + l16;
        float bv = bias[n];
#pragma unroll
        for (int mb = 0; mb < 2; ++mb) {
#pragma unroll
            for (int r = 0; r < 4; ++r) {
                long grow = (long)row0 + w * 32 + mb * 16 + lg * 4 + r;
                if (grow < N) {
                    float v = acc[mb][nb][r] + bv;
                    v = v > 0.f ? v : 0.f;
                    if (OUT_F32)
                        ((float*)outv)[(size_t)grow * D + n] = v;
                    else
                        ((__hip_bfloat16*)outv)[(size_t)grow * D + n] =
                            __float2bfloat16(v);
                }
            }
        }
    }
}

extern "C" void kernel_launch(void* const* d_in, const int* in_sizes, int n_in,
                              void* d_out, int out_size, void* d_ws, size_t ws_size,
                              hipStream_t stream) {
    const float* x    = (const float*)d_in[0];
    const int*   ei   = (const int*)d_in[1];
    const float* attr = (const float*)d_in[2];
    const float* Wf   = (const float*)d_in[3];
    const float* bf   = (const float*)d_in[4];
    const float* cw   = (const float*)d_in[5];  // [3][2][128][128]
    const float* cr   = (const float*)d_in[6];  // [3][128][128]
    const float* cb   = (const float*)d_in[7];  // [3][128]
    const int* src  = ei;
    const int* dstv = ei + NE;

    // workspace layout (bytes)
    char* p = (char*)d_ws;
    __hip_bfloat16* h0   = (__hip_bfloat16*)p; p += (size_t)NN * D * 2;
    __hip_bfloat16* h1   = (__hip_bfloat16*)p; p += (size_t)NN * D * 2;
    __hip_bfloat16* aggb = (__hip_bfloat16*)p; p += (size_t)2 * NN * D * 2;
    __hip_bfloat16* wt   = (__hip_bfloat16*)p; p += (size_t)NWT * 2;
    float* inv  = (float*)p;                p += (size_t)2 * NN * 4;
    // --- contiguous zero-init region: cnt | hist | total ---
    int*   cnt  = (int*)p;                  p += (size_t)2 * NN * 4;
    int*   hist = (int*)p;                  p += (size_t)NBIN * 4;
    int*   total= (int*)p;                  p += 4;
    // -------------------------------------------------------
    int*   off  = (int*)p;                  p += (size_t)2 * NN * 4;
    int*   cur  = (int*)p;                  p += (size_t)2 * NN * 4;
    int*   bcur = (int*)p;                  p += (size_t)NBIN * 4;
    int*   order= (int*)p;                  p += (size_t)NN * 4;
    int*   srcs = (int*)p;

    float* outp = (float*)d_out;

    // ---- layer-invariant preprocessing ----
    hipMemsetAsync(cnt, 0, (size_t)(2 * NN + NBIN + 1) * sizeof(int), stream);
    k_pre1<<<NEB + NWB, 256, 0, stream>>>(attr, dstv, cnt, Wf, cw, cr, wt);
    k_pre2<<<(NN + 255) / 256, 256, 0, stream>>>(cnt, inv, off, cur, total, hist);
    k_pre3<<<1, NBIN, 0, stream>>>(hist, bcur);
    k_pre4<<<(NN + 255) / 256, 256, 0, stream>>>(cnt, bcur, order);
    k_fill<<<NEB, 256, 0, stream>>>(attr, src, dstv, cur, srcs, NE);

    // input projection (f32 x read directly)
    k_gemm_proj<<<(NN + 127) / 128, 256, 0, stream>>>(x, wt, bf, h0, NN);

    const int gblocks = (NN + BM - 1) / BM;
    const int ablocks = ((NN + 3) / 4 * 64 + 255) / 256;  // 16-lane group/node
    for (int l = 0; l < 3; ++l) {
        const __hip_bfloat16* hin = (l == 1) ? h1 : h0;
        k_aggregate<<<ablocks, 256, 0, stream>>>(hin, srcs, off, cnt, inv,
                                                 order, aggb);
        const __hip_bfloat16* wl = wt + 16384 + (size_t)l * 49152;
        const float* bl = cb + (size_t)l * D;
        if (l == 2) {
            k_gemm_mfma<true><<<gblocks, 256, 0, stream>>>(
                hin, 128, aggb, 256, aggb + 128, 256, wl, bl, outp, NN);
        } else {
            __hip_bfloat16* hout = (l == 0) ? h1 : h0;
            k_gemm_mfma<false><<<gblocks, 256, 0, stream>>>(
                hin, 128, aggb, 256, aggb + 128, 256, wl, bl, hout, NN);
        }
    }
}

// Round 13
// 228.217 us; speedup vs baseline: 2.3418x; 1.0314x over previous
//
#include <hip/hip_runtime.h>
#include <hip/hip_bf16.h>

#define NN 50000
#define NE 600000
#define D 128
#define NREL 2
#define BM 128

typedef __attribute__((ext_vector_type(8))) short bf16x8;   // 8 bf16 (4 VGPRs)
typedef __attribute__((ext_vector_type(4))) float f32x4;    // 4 fp32 acc
typedef __attribute__((ext_vector_type(2))) float f32x2;    // packed pair

__device__ __forceinline__ float bf2f(short s) {
    return __uint_as_float(((unsigned int)(unsigned short)s) << 16);
}
__device__ __forceinline__ bf16x8 pack_bf8(const float* a) {
    union { bf16x8 v; __hip_bfloat162 h2[4]; } o;
#pragma unroll
    for (int i = 0; i < 4; i++)
        o.h2[i] = __float22bfloat162_rn(make_float2(a[2 * i], a[2 * i + 1]));
    return o.v;
}

#define NEB ((NE + 255) / 256)          // edge blocks
#define NWT (16384 + 3 * 49152)         // wt elements
#define NWB ((NWT + 255) / 256)         // prep_w blocks

// ---------------- fused: edge count (blocks < NEB) + weight prep (rest) ------
// bucket key = dst*2 + rel (node-major, rel minor)
__global__ void k_pre1(const float* __restrict__ attr,
                       const int* __restrict__ dst,
                       int* __restrict__ cnt,
                       const float* __restrict__ Wf,
                       const float* __restrict__ cw,
                       const float* __restrict__ cr,
                       __hip_bfloat16* __restrict__ wt) {
    if (blockIdx.x < NEB) {
        int i = blockIdx.x * blockDim.x + threadIdx.x;
        if (i >= NE) return;
        float2 a = reinterpret_cast<const float2*>(attr)[i];
        int r = (a.y > a.x) ? 1 : 0;   // argmax, first-index tiebreak
        atomicAdd(&cnt[dst[i] * 2 + r], 1);
    } else {
        int idx = (blockIdx.x - NEB) * blockDim.x + threadIdx.x;
        if (idx >= NWT) return;
        float v;
        if (idx < 16384) {
            int n = idx >> 7, k = idx & 127;
            v = Wf[k * 128 + n];
        } else {
            int j = idx - 16384;
            int l = j / 49152; j %= 49152;
            int n = j / 384, k = j % 384;
            if (k < 128)      v = cr[((size_t)l * 128 + k) * 128 + n];
            else if (k < 256) v = cw[((size_t)(l * 2 + 0) * 128 + (k - 128)) * 128 + n];
            else              v = cw[((size_t)(l * 2 + 1) * 128 + (k - 256)) * 128 + n];
        }
        wt[idx] = __float2bfloat16(v);
    }
}

// ---------------- per-NODE allocator + packed metadata -----------------------
// meta[i] = {start, c0 | (c01<<16), inv0_bits, inv1_bits}: ONE 16B load in the
// aggregate instead of 5 scattered scalar loads (off, 2*cnt, 2*inv).
// R11 lesson kept: only single-address atomics here (wave-coalesced by the
// compiler); no divergent hot-bin atomics.
__global__ void k_pre2(const int* __restrict__ cnt,
                       int* __restrict__ cur, int* __restrict__ total,
                       int4* __restrict__ meta) {
    int i = blockIdx.x * blockDim.x + threadIdx.x;
    if (i >= NN) return;
    int c0 = cnt[2 * i], c1 = cnt[2 * i + 1];
    int c01 = c0 + c1;
    float i0 = 1.0f / (float)(c0 > 1 ? c0 : 1);
    float i1 = 1.0f / (float)(c1 > 1 ? c1 : 1);
    int o = atomicAdd(total, c01);       // single address: wave-coalesced
    cur[2 * i] = o;
    cur[2 * i + 1] = o + c0;
    meta[i] = make_int4(o, c0 | (c01 << 16),
                        __float_as_int(i0), __float_as_int(i1));
}

// ---------------- fill CSR: srcs[pos] = src[e], bucketed by (dst,rel) --------
__global__ void k_fill(const float* __restrict__ attr,
                       const int* __restrict__ src, const int* __restrict__ dst,
                       int* __restrict__ cursor, int* __restrict__ srcs, int E) {
    int i = blockIdx.x * blockDim.x + threadIdx.x;
    if (i >= E) return;
    float2 a = reinterpret_cast<const float2*>(attr)[i];
    int r = (a.y > a.x) ? 1 : 0;
    int pos = atomicAdd(&cursor[dst[i] * 2 + r], 1);
    srcs[pos] = src[i];
}

// ---------------- aggregation: one 16-lane group per NODE, 4 nodes/wave ------
// Group g owns node wid*4+g; 16 lanes cover the 256B row (16B/lane). Loop
// bound cmax = wave max of c01 -> wave-uniform, so every __shfl runs with all
// 64 lanes active (R5 lesson). Relation mask + 1/deg fold into a per-edge
// scalar weight -> v_pk_fma_f32 accumulate (~2 VALU/element). No cross-group
// reduce; stores are 4 consecutive nodes = 1KB contiguous per wave.
__global__ __launch_bounds__(256)
void k_aggregate(const __hip_bfloat16* __restrict__ h,
                 const int* __restrict__ srcs,
                 const int4* __restrict__ meta,
                 __hip_bfloat16* __restrict__ agg) {
    int wid = (blockIdx.x * blockDim.x + threadIdx.x) >> 6;   // wave id
    int lane = threadIdx.x & 63;
    int nb = wid * 4;
    if (nb >= NN) return;                  // whole-wave uniform
    const int g = lane >> 4, l16 = lane & 15;
    int node = nb + g;
    bool nv = node < NN;
    int nn = nv ? node : (NN - 1);

    int4 m = meta[nn];                     // ONE packed metadata load
    int st = m.x;
    int c0  = nv ? (m.y & 0xffff) : 0;
    int c01 = nv ? (m.y >> 16) : 0;
    float i0 = __int_as_float(m.z), i1 = __int_as_float(m.w);

    int sv = (l16 < c01) ? srcs[st + l16] : 0;   // group-coalesced index load

    int cm = c01;                                 // wave max of c01
    cm = max(cm, __shfl_xor(cm, 16));
    cm = max(cm, __shfl_xor(cm, 32));

    f32x2 a0[4], a1[4];
#pragma unroll
    for (int p = 0; p < 4; p++) { a0[p] = (f32x2)(0.f); a1[p] = (f32x2)(0.f); }

    const char* hb = (const char*)h;
    if (cm <= 16) {                               // common case
        for (int j = 0; j < cm; j += 4) {         // wave-uniform trip count
            int s[4]; float w0[4], w1[4];
#pragma unroll
            for (int q = 0; q < 4; ++q) {
                int jj = j + q;
                int t = __shfl(sv, (lane & 48) + (jj & 15));  // full-exec shfl
                s[q] = (jj < c01) ? t : 0;        // clamp: row 0 valid, L1-hot
                w0[q] = (jj < c0) ? i0 : 0.f;
                w1[q] = (jj >= c0 && jj < c01) ? i1 : 0.f;
            }
            uint4 v[4];
#pragma unroll
            for (int q = 0; q < 4; ++q)           // 4 independent gathers/lane
                v[q] = *reinterpret_cast<const uint4*>(
                    hb + (size_t)s[q] * 256 + l16 * 16);
#pragma unroll
            for (int q = 0; q < 4; ++q) {
                f32x2 w0v = {w0[q], w0[q]}, w1v = {w1[q], w1[q]};
                unsigned uu[4] = {v[q].x, v[q].y, v[q].z, v[q].w};
#pragma unroll
                for (int p = 0; p < 4; ++p) {
                    f32x2 val;
                    val.x = __uint_as_float(uu[p] << 16);
                    val.y = __uint_as_float(uu[p] & 0xffff0000u);
                    a0[p] += val * w0v;           // v_pk_fma_f32
                    a1[p] += val * w1v;
                }
            }
        }
    } else {                                      // rare hub-wave path
        for (int j = 0; j < cm; j += 4) {
            int s[4]; float w0[4], w1[4];
#pragma unroll
            for (int q = 0; q < 4; ++q) {
                int jj = j + q;
                int t = __shfl(sv, (lane & 48) + (jj & 15));
                s[q] = t;
                if (jj >= 16 && jj < c01) s[q] = srcs[st + jj];
                if (jj >= c01) s[q] = 0;
                w0[q] = (jj < c0) ? i0 : 0.f;
                w1[q] = (jj >= c0 && jj < c01) ? i1 : 0.f;
            }
            uint4 v[4];
#pragma unroll
            for (int q = 0; q < 4; ++q)
                v[q] = *reinterpret_cast<const uint4*>(
                    hb + (size_t)s[q] * 256 + l16 * 16);
#pragma unroll
            for (int q = 0; q < 4; ++q) {
                f32x2 w0v = {w0[q], w0[q]}, w1v = {w1[q], w1[q]};
                unsigned uu[4] = {v[q].x, v[q].y, v[q].z, v[q].w};
#pragma unroll
                for (int p = 0; p < 4; ++p) {
                    f32x2 val;
                    val.x = __uint_as_float(uu[p] << 16);
                    val.y = __uint_as_float(uu[p] & 0xffff0000u);
                    a0[p] += val * w0v;
                    a1[p] += val * w1v;
                }
            }
        }
    }

    if (!nv) return;
    float t0[8], t1[8];
#pragma unroll
    for (int p = 0; p < 4; p++) {
        t0[2 * p] = a0[p].x; t0[2 * p + 1] = a0[p].y;
        t1[2 * p] = a1[p].x; t1[2 * p + 1] = a1[p].y;
    }
    __hip_bfloat16* dp = agg + (size_t)node * 256;
    *reinterpret_cast<bf16x8*>(dp + l16 * 8)       = pack_bf8(t0);
    *reinterpret_cast<bf16x8*>(dp + 128 + l16 * 8) = pack_bf8(t1);
}

// ---------------- proj GEMM: h0 = relu(x_f32 @ Wtp^T + bf), bf16 out ---------
__global__ __launch_bounds__(256)
void k_gemm_proj(const float* __restrict__ X,
                 const __hip_bfloat16* __restrict__ Wt,   // [128][128]
                 const float* __restrict__ bias,
                 __hip_bfloat16* __restrict__ out, int N) {
    __shared__ uint4 sB4[1024];            // 16 KB
    char* sB = (char*)sB4;
    const int tid = threadIdx.x;
    const int w = tid >> 6;
    const int l16 = tid & 15, lg = (tid & 63) >> 4;

    f32x4 acc[2][8];
#pragma unroll
    for (int m = 0; m < 2; m++)
#pragma unroll
        for (int n = 0; n < 8; n++) acc[m][n] = (f32x4)(0.f);

    const int row0 = blockIdx.x * 128;
#pragma unroll
    for (int kb = 0; kb < 2; ++kb) {
        bf16x8 afr[2][2];
#pragma unroll
        for (int mb = 0; mb < 2; ++mb)
#pragma unroll
            for (int kk = 0; kk < 2; ++kk) {
                int r = row0 + w * 32 + mb * 16 + l16;
                if (r >= N) r = N - 1;
                const float* p = X + (size_t)r * D + kb * 64 + kk * 32 + lg * 8;
                float4 u0 = reinterpret_cast<const float4*>(p)[0];
                float4 u1 = reinterpret_cast<const float4*>(p)[1];
                float t[8] = {u0.x, u0.y, u0.z, u0.w, u1.x, u1.y, u1.z, u1.w};
                afr[mb][kk] = pack_bf8(t);
            }
        __syncthreads();
        {
            int trow = tid >> 3, tb = (tid & 7) * 16;
#pragma unroll
            for (int p = 0; p < 4; ++p) {
                int rr = trow + p * 32;
                uint4 v = *reinterpret_cast<const uint4*>(
                    (const char*)(Wt + (size_t)rr * 128 + kb * 64) + tb);
                *reinterpret_cast<uint4*>(sB + rr * 128 + (tb ^ ((rr & 7) << 4))) = v;
            }
        }
        __syncthreads();
#pragma unroll
        for (int kk = 0; kk < 2; ++kk)
#pragma unroll
            for (int nb = 0; nb < 8; ++nb) {
                int brow = nb * 16 + l16;
                int bcol = kk * 64 + lg * 16;
                bf16x8 bfr = *reinterpret_cast<const bf16x8*>(
                    sB + brow * 128 + (bcol ^ ((brow & 7) << 4)));
                acc[0][nb] = __builtin_amdgcn_mfma_f32_16x16x32_bf16(
                    afr[0][kk], bfr, acc[0][nb], 0, 0, 0);
                acc[1][nb] = __builtin_amdgcn_mfma_f32_16x16x32_bf16(
                    afr[1][kk], bfr, acc[1][nb], 0, 0, 0);
            }
    }
#pragma unroll
    for (int nb = 0; nb < 8; ++nb) {
        int n = nb * 16 + l16;
        float bv = bias[n];
#pragma unroll
        for (int mb = 0; mb < 2; ++mb)
#pragma unroll
            for (int r = 0; r < 4; ++r) {
                int grow = row0 + w * 32 + mb * 16 + lg * 4 + r;
                if (grow < N) {
                    float v = acc[mb][nb][r] + bv;
                    v = v > 0.f ? v : 0.f;
                    out[(size_t)grow * D + n] = __float2bfloat16(v);
                }
            }
    }
}

// ---------------- MFMA GEMM: out = relu([A0|A1|A2] @ Wt^T + bias) ------------
// Per-chunk row stride (elements): hin is 128, agg (interleaved) is 256.
template <bool OUT_F32>
__global__ __launch_bounds__(256)
void k_gemm_mfma(const __hip_bfloat16* __restrict__ A0, int sA0,
                 const __hip_bfloat16* __restrict__ A1, int sA1,
                 const __hip_bfloat16* __restrict__ A2, int sA2,
                 const __hip_bfloat16* __restrict__ Wt,   // [128][384]
                 const float* __restrict__ bias,
                 void* __restrict__ outv, int N) {
    __shared__ uint4 sB4[1024];            // 16 KB
    char* sB = (char*)sB4;
    const int tid = threadIdx.x;
    const int w = tid >> 6;
    const int l16 = tid & 15, lg = (tid & 63) >> 4;
    const __hip_bfloat16* As[3] = {A0, A1, A2};
    const int strides[3] = {sA0, sA1, sA2};

    f32x4 acc[2][8];
#pragma unroll
    for (int m = 0; m < 2; m++)
#pragma unroll
        for (int n = 0; n < 8; n++) acc[m][n] = (f32x4)(0.f);

    const size_t row0 = (size_t)blockIdx.x * BM;
#pragma unroll
    for (int kb = 0; kb < 6; ++kb) {
        const __hip_bfloat16* Ac = As[kb >> 1];
        const int strideC = strides[kb >> 1];
        const int koff = (kb & 1) * 64;
        bf16x8 afr[2][2];
#pragma unroll
        for (int mb = 0; mb < 2; ++mb)
#pragma unroll
            for (int kk = 0; kk < 2; ++kk) {
                int r = (int)row0 + w * 32 + mb * 16 + l16;
                if (r >= N) r = N - 1;              // clamped; store-guarded later
                afr[mb][kk] = *reinterpret_cast<const bf16x8*>(
                    Ac + (size_t)r * strideC + koff + kk * 32 + lg * 8);
            }
        __syncthreads();   // previous kb's sB reads complete
        {
            int trow = tid >> 3;
            int tb = (tid & 7) * 16;               // byte col within 128B row
#pragma unroll
            for (int p = 0; p < 4; ++p) {
                int rr = trow + p * 32;
                uint4 v = *reinterpret_cast<const uint4*>(
                    (const char*)(Wt + (size_t)rr * 384 + kb * 64) + tb);
                *reinterpret_cast<uint4*>(sB + rr * 128 + (tb ^ ((rr & 7) << 4))) = v;
            }
        }
        __syncthreads();
#pragma unroll
        for (int kk = 0; kk < 2; ++kk) {
#pragma unroll
            for (int nb = 0; nb < 8; ++nb) {
                int brow = nb * 16 + l16;
                int bcol = kk * 64 + lg * 16;
                bf16x8 bfr = *reinterpret_cast<const bf16x8*>(
                    sB + brow * 128 + (bcol ^ ((brow & 7) << 4)));
                acc[0][nb] = __builtin_amdgcn_mfma_f32_16x16x32_bf16(
                    afr[0][kk], bfr, acc[0][nb], 0, 0, 0);
                acc[1][nb] = __builtin_amdgcn_mfma_f32_16x16x32_bf16(
                    afr[1][kk], bfr, acc[1][nb], 0, 0, 0);
            }
        }
    }
#pragma unroll
    for (int nb = 0; nb < 8; ++nb) {
        int n = nb * 16 + l16;
        float bv = bias[n];
#pragma unroll
        for (int mb = 0; mb < 2; ++mb) {
#pragma unroll
            for (int r = 0; r < 4; ++r) {
                long grow = (long)row0 + w * 32 + mb * 16 + lg * 4 + r;
                if (grow < N) {
                    float v = acc[mb][nb][r] + bv;
                    v = v > 0.f ? v : 0.f;
                    if (OUT_F32)
                        ((float*)outv)[(size_t)grow * D + n] = v;
                    else
                        ((__hip_bfloat16*)outv)[(size_t)grow * D + n] =
                            __float2bfloat16(v);
                }
            }
        }
    }
}

extern "C" void kernel_launch(void* const* d_in, const int* in_sizes, int n_in,
                              void* d_out, int out_size, void* d_ws, size_t ws_size,
                              hipStream_t stream) {
    const float* x    = (const float*)d_in[0];
    const int*   ei   = (const int*)d_in[1];
    const float* attr = (const float*)d_in[2];
    const float* Wf   = (const float*)d_in[3];
    const float* bf   = (const float*)d_in[4];
    const float* cw   = (const float*)d_in[5];  // [3][2][128][128]
    const float* cr   = (const float*)d_in[6];  // [3][128][128]
    const float* cb   = (const float*)d_in[7];  // [3][128]
    const int* src  = ei;
    const int* dstv = ei + NE;

    // workspace layout (bytes)
    char* p = (char*)d_ws;
    __hip_bfloat16* h0   = (__hip_bfloat16*)p; p += (size_t)NN * D * 2;
    __hip_bfloat16* h1   = (__hip_bfloat16*)p; p += (size_t)NN * D * 2;
    __hip_bfloat16* aggb = (__hip_bfloat16*)p; p += (size_t)2 * NN * D * 2;
    __hip_bfloat16* wt   = (__hip_bfloat16*)p; p += (size_t)NWT * 2;
    // --- contiguous zero-init region: cnt | total ---
    int*   cnt  = (int*)p;                  p += (size_t)2 * NN * 4;
    int*   total= (int*)p;                  p += 4;
    // ------------------------------------------------
    int*   cur  = (int*)p;                  p += (size_t)2 * NN * 4;
    int4*  meta = (int4*)p;                 p += (size_t)NN * 16;
    int*   srcs = (int*)p;

    float* outp = (float*)d_out;

    // ---- layer-invariant preprocessing ----
    hipMemsetAsync(cnt, 0, (size_t)(2 * NN + 1) * sizeof(int), stream);
    k_pre1<<<NEB + NWB, 256, 0, stream>>>(attr, dstv, cnt, Wf, cw, cr, wt);
    k_pre2<<<(NN + 255) / 256, 256, 0, stream>>>(cnt, cur, total, meta);
    k_fill<<<NEB, 256, 0, stream>>>(attr, src, dstv, cur, srcs, NE);

    // input projection (f32 x read directly)
    k_gemm_proj<<<(NN + 127) / 128, 256, 0, stream>>>(x, wt, bf, h0, NN);

    const int gblocks = (NN + BM - 1) / BM;
    const int ablocks = ((NN + 3) / 4 * 64 + 255) / 256;  // 16-lane group/node
    for (int l = 0; l < 3; ++l) {
        const __hip_bfloat16* hin = (l == 1) ? h1 : h0;
        k_aggregate<<<ablocks, 256, 0, stream>>>(hin, srcs, meta, aggb);
        const __hip_bfloat16* wl = wt + 16384 + (size_t)l * 49152;
        const float* bl = cb + (size_t)l * D;
        if (l == 2) {
            k_gemm_mfma<true><<<gblocks, 256, 0, stream>>>(
                hin, 128, aggb, 256, aggb + 128, 256, wl, bl, outp, NN);
        } else {
            __hip_bfloat16* hout = (l == 0) ? h1 : h0;
            k_gemm_mfma<false><<<gblocks, 256, 0, stream>>>(
                hin, 128, aggb, 256, aggb + 128, 256, wl, bl, hout, NN);
        }
    }
}